// Round 1
// baseline (122.785 us; speedup 1.0000x reference)
//
#include <hip/hip_runtime.h>

#define BATCH 64
#define NSAMP 1500
#define NFREQ 1251

// ---------------------------------------------------------------------------
// Kernel 1: psd[b,f] = (sum_n x[b,n] cos(2*pi*f_v[f]*n/fs[b]))^2 + (... sin)^2
// One thread per (b, f). x[b,:] staged in LDS (all lanes read same element
// per iteration -> LDS broadcast, conflict-free). Phase tracked in
// REVOLUTIONS: r = n * (f/fs); fract(r) in [0,1); v_sin/v_cos take revs.
// ---------------------------------------------------------------------------
__global__ __launch_bounds__(64) void psd_kernel(
    const float* __restrict__ x,          // [B,N]
    const float* __restrict__ fs,         // [B]
    const float* __restrict__ sampling_f, // [1]
    const float* __restrict__ f_range,    // [>=1], f_min first
    float* __restrict__ psd)              // [B,F]
{
    __shared__ float xs[NSAMP];
    const int b   = blockIdx.x;
    const int tid = threadIdx.x;

    const float* xb = x + b * NSAMP;
    for (int i = tid; i < NSAMP; i += 64) xs[i] = xb[i];
    __syncthreads();

    const int fidx = blockIdx.y * 64 + tid;
    if (fidx >= NFREQ) return;

    // Replicate numpy arange fill: delta = fl(f_min+step) - f_min (exact),
    // f_values[i] = f_min + i*delta, all in fp32.
    const float f_min = f_range[0];
    const float step  = sampling_f[0];
    const float delta = (f_min + step) - f_min;
    const float fv    = f_min + (float)fidx * delta;

    const float inv_fs = 1.0f / fs[b];
    const float rstep  = fv * inv_fs;     // revolutions advanced per sample

    float acc_c = 0.0f, acc_s = 0.0f;
#pragma unroll 4
    for (int n = 0; n < NSAMP; ++n) {
        float r = (float)n * rstep;
        r -= floorf(r);                    // [0,1) revolutions
        float sn = __builtin_amdgcn_sinf(r);
        float cs = __builtin_amdgcn_cosf(r);
        float xv = xs[n];
        acc_c = fmaf(xv, cs, acc_c);
        acc_s = fmaf(xv, sn, acc_s);
    }
    psd[b * NFREQ + fidx] = acc_c * acc_c + acc_s * acc_s;
}

// ---------------------------------------------------------------------------
// Kernel 2: per-sample loss. One block per b.
//   idx   = first argmin_i |f_values[i] - f_true[b]|   (np.argmin semantics)
//   lse   = max + log(sum exp(psd - max))
//   per_sample[b] = -log(exp(psd[idx] - max)/sumexp + 1e-8)
// ---------------------------------------------------------------------------
__global__ __launch_bounds__(256) void loss_kernel(
    const float* __restrict__ psd,        // [B,F]
    const float* __restrict__ f_true,     // [B]
    const float* __restrict__ sampling_f,
    const float* __restrict__ f_range,
    float* __restrict__ per_sample)       // [B]
{
    const int b   = blockIdx.x;
    const int tid = threadIdx.x;
    const float* p = psd + b * NFREQ;

    __shared__ float smax[256];
    __shared__ float ssum[256];
    __shared__ float sdist[256];
    __shared__ int   sidx[256];

    const float f_min = f_range[0];
    const float step  = sampling_f[0];
    const float delta = (f_min + step) - f_min;
    const float ft    = f_true[b];

    float vmax  = -INFINITY;
    float bestd = INFINITY;
    int   besti = NFREQ;
    for (int i = tid; i < NFREQ; i += 256) {
        float v = p[i];
        vmax = fmaxf(vmax, v);
        float fv = f_min + (float)i * delta;
        float d  = fabsf(fv - ft);
        if (d < bestd) { bestd = d; besti = i; }   // i increases per thread
    }
    smax[tid] = vmax; sdist[tid] = bestd; sidx[tid] = besti;
    __syncthreads();
    for (int s = 128; s > 0; s >>= 1) {
        if (tid < s) {
            smax[tid] = fmaxf(smax[tid], smax[tid + s]);
            float d2 = sdist[tid + s]; int i2 = sidx[tid + s];
            // first-occurrence argmin: ties pick smaller index
            if (d2 < sdist[tid] || (d2 == sdist[tid] && i2 < sidx[tid])) {
                sdist[tid] = d2; sidx[tid] = i2;
            }
        }
        __syncthreads();
    }
    const float gmax = smax[0];
    const int   idx  = sidx[0];

    float se = 0.0f;
    for (int i = tid; i < NFREQ; i += 256) se += __expf(p[i] - gmax);
    ssum[tid] = se;
    __syncthreads();
    for (int s = 128; s > 0; s >>= 1) {
        if (tid < s) ssum[tid] += ssum[tid + s];
        __syncthreads();
    }

    if (tid == 0) {
        float sumexp = ssum[0];
        float sm = __expf(p[idx] - gmax) / sumexp;
        per_sample[b] = -logf(sm + 1e-8f);
    }
}

// ---------------------------------------------------------------------------
// Kernel 3: mean over 64 per-sample losses -> d_out[0]. One wave.
// ---------------------------------------------------------------------------
__global__ __launch_bounds__(64) void mean_kernel(
    const float* __restrict__ per_sample, float* __restrict__ out)
{
    float v = per_sample[threadIdx.x];
    for (int off = 32; off > 0; off >>= 1) v += __shfl_down(v, off);
    if (threadIdx.x == 0) out[0] = v * (1.0f / (float)BATCH);
}

extern "C" void kernel_launch(void* const* d_in, const int* in_sizes, int n_in,
                              void* d_out, int out_size, void* d_ws, size_t ws_size,
                              hipStream_t stream) {
    const float* x          = (const float*)d_in[0];
    const float* f_true     = (const float*)d_in[1];
    const float* fs         = (const float*)d_in[2];
    // d_in[3] = deltas (unused by the loss)
    const float* sampling_f = (const float*)d_in[4];
    const float* f_range    = (const float*)d_in[5];

    float* psd        = (float*)d_ws;            // [B*F] floats = 320,256 B
    float* per_sample = psd + BATCH * NFREQ;     // [B]

    dim3 g1(BATCH, (NFREQ + 63) / 64);           // 64 x 20 = 1280 blocks
    psd_kernel<<<g1, 64, 0, stream>>>(x, fs, sampling_f, f_range, psd);
    loss_kernel<<<BATCH, 256, 0, stream>>>(psd, f_true, sampling_f, f_range, per_sample);
    mean_kernel<<<1, 64, 0, stream>>>(per_sample, (float*)d_out);
}

// Round 2
// 77.232 us; speedup vs baseline: 1.5898x; 1.5898x over previous
//
#include <hip/hip_runtime.h>

#define BATCH 64
#define NSAMP 1500
#define NFREQ 1251
#define NSEG  5
#define SEGLEN 300          // NSEG*SEGLEN == NSAMP, SEGLEN % 4 == 0
#define FCHUNKS 20          // ceil(NFREQ/64)

// ---------------------------------------------------------------------------
// Kernel 1: Goertzel partial sums.
// Thread = (b, f); block z = time segment seg (300 samples).
//   s_k = x_k + 2cos(w) s_{k-1} - s_{k-2}        (2 VALU ops / sample)
//   C_loc = cos((M-1)w) s1 - cos(Mw) s2
//   S_loc = sin((M-1)w) s1 - sin(Mw) s2
// then rotate by the segment start phase n0*w and store partial (C,S).
// All trig in REVOLUTIONS via v_cos/v_sin (fract-reduced), ~7 ops/thread.
// ---------------------------------------------------------------------------
__global__ __launch_bounds__(64) void goertzel_kernel(
    const float* __restrict__ x,          // [B,N]
    const float* __restrict__ fs,         // [B]
    const float* __restrict__ sampling_f, // [1]
    const float* __restrict__ f_range,    // f_min first
    float* __restrict__ pc,               // [B,NSEG,NFREQ] partial cos sums
    float* __restrict__ ps)               // [B,NSEG,NFREQ] partial sin sums
{
    __shared__ float4 xs4[SEGLEN / 4];    // 300 floats = 75 float4
    const int b   = blockIdx.x;
    const int seg = blockIdx.z;
    const int tid = threadIdx.x;
    const int n0  = seg * SEGLEN;

    const float4* xg = reinterpret_cast<const float4*>(x + b * NSAMP + n0);
    for (int i = tid; i < SEGLEN / 4; i += 64) xs4[i] = xg[i];
    __syncthreads();

    const int fidx = blockIdx.y * 64 + tid;
    if (fidx >= NFREQ) return;

    // numpy arange fill semantics (matched exactly in round 1)
    const float f_min = f_range[0];
    const float step  = sampling_f[0];
    const float delta = (f_min + step) - f_min;
    const float fv    = f_min + (float)fidx * delta;

    const float rho = fv / fs[b];                 // revolutions per sample
    float rf = rho - floorf(rho);
    const float coef = 2.0f * __builtin_amdgcn_cosf(rf);

    float s1 = 0.0f, s2 = 0.0f;
#pragma unroll 5
    for (int k = 0; k < SEGLEN / 4; ++k) {
        float4 v = xs4[k];
        float t;
        t = fmaf(coef, s1, v.x - s2); s2 = s1; s1 = t;
        t = fmaf(coef, s1, v.y - s2); s2 = s1; s1 = t;
        t = fmaf(coef, s1, v.z - s2); s2 = s1; s1 = t;
        t = fmaf(coef, s1, v.w - s2); s2 = s1; s1 = t;
    }

    // extraction at segment end (M = SEGLEN samples processed)
    float aM  = (float)SEGLEN * rho;        aM  -= floorf(aM);
    float aM1 = (float)(SEGLEN - 1) * rho;  aM1 -= floorf(aM1);
    float a0  = (float)n0 * rho;            a0  -= floorf(a0);
    const float cM  = __builtin_amdgcn_cosf(aM);
    const float sM  = __builtin_amdgcn_sinf(aM);
    const float cM1 = __builtin_amdgcn_cosf(aM1);
    const float sM1 = __builtin_amdgcn_sinf(aM1);
    const float c0  = __builtin_amdgcn_cosf(a0);
    const float s0  = __builtin_amdgcn_sinf(a0);

    const float Cl = cM1 * s1 - cM * s2;
    const float Sl = sM1 * s1 - sM * s2;
    // rotate to absolute phase (segment starts at sample n0)
    const float C = c0 * Cl - s0 * Sl;
    const float S = s0 * Cl + c0 * Sl;

    pc[(b * NSEG + seg) * NFREQ + fidx] = C;
    ps[(b * NSEG + seg) * NFREQ + fidx] = S;
}

// ---------------------------------------------------------------------------
// Kernel 2: assemble psd from partials, per-sample loss, fused mean via
// atomicAdd into d_out (pre-zeroed with hipMemsetAsync).
// ---------------------------------------------------------------------------
__global__ __launch_bounds__(256) void loss_kernel(
    const float* __restrict__ pc,         // [B,NSEG,NFREQ]
    const float* __restrict__ ps,
    const float* __restrict__ f_true,     // [B]
    const float* __restrict__ sampling_f,
    const float* __restrict__ f_range,
    float* __restrict__ out)              // [1], zero-initialized
{
    const int b   = blockIdx.x;
    const int tid = threadIdx.x;

    __shared__ float psd_s[NFREQ];
    __shared__ float smax[256];
    __shared__ float ssum[256];
    __shared__ float sdist[256];
    __shared__ int   sidx[256];

    const float f_min = f_range[0];
    const float step  = sampling_f[0];
    const float delta = (f_min + step) - f_min;
    const float ft    = f_true[b];

    float vmax  = -INFINITY;
    float bestd = INFINITY;
    int   besti = NFREQ;
    for (int i = tid; i < NFREQ; i += 256) {
        float c = 0.0f, s = 0.0f;
#pragma unroll
        for (int g = 0; g < NSEG; ++g) {
            c += pc[(b * NSEG + g) * NFREQ + i];
            s += ps[(b * NSEG + g) * NFREQ + i];
        }
        float v = fmaf(c, c, s * s);
        psd_s[i] = v;
        vmax = fmaxf(vmax, v);
        float fv = f_min + (float)i * delta;
        float d  = fabsf(fv - ft);
        if (d < bestd) { bestd = d; besti = i; }   // per-thread first min
    }
    smax[tid] = vmax; sdist[tid] = bestd; sidx[tid] = besti;
    __syncthreads();
    for (int s = 128; s > 0; s >>= 1) {
        if (tid < s) {
            smax[tid] = fmaxf(smax[tid], smax[tid + s]);
            float d2 = sdist[tid + s]; int i2 = sidx[tid + s];
            if (d2 < sdist[tid] || (d2 == sdist[tid] && i2 < sidx[tid])) {
                sdist[tid] = d2; sidx[tid] = i2;   // np.argmin: first occurrence
            }
        }
        __syncthreads();
    }
    const float gmax = smax[0];
    const int   idx  = sidx[0];

    float se = 0.0f;
    for (int i = tid; i < NFREQ; i += 256) se += __expf(psd_s[i] - gmax);
    ssum[tid] = se;
    __syncthreads();
    for (int s = 128; s > 0; s >>= 1) {
        if (tid < s) ssum[tid] += ssum[tid + s];
        __syncthreads();
    }

    if (tid == 0) {
        float sm = __expf(psd_s[idx] - gmax) / ssum[0];
        float per = -logf(sm + 1e-8f);
        atomicAdd(out, per * (1.0f / (float)BATCH));
    }
}

extern "C" void kernel_launch(void* const* d_in, const int* in_sizes, int n_in,
                              void* d_out, int out_size, void* d_ws, size_t ws_size,
                              hipStream_t stream) {
    const float* x          = (const float*)d_in[0];
    const float* f_true     = (const float*)d_in[1];
    const float* fs         = (const float*)d_in[2];
    // d_in[3] = deltas (unused)
    const float* sampling_f = (const float*)d_in[4];
    const float* f_range    = (const float*)d_in[5];

    float* pc = (float*)d_ws;                         // [B*NSEG*NFREQ]
    float* ps = pc + BATCH * NSEG * NFREQ;            // [B*NSEG*NFREQ]
    // total ws use: 2*64*5*1251*4 B = 3.2 MB

    hipMemsetAsync(d_out, 0, sizeof(float), stream);

    dim3 g1(BATCH, FCHUNKS, NSEG);                    // 64 x 20 x 5 = 6400 waves
    goertzel_kernel<<<g1, 64, 0, stream>>>(x, fs, sampling_f, f_range, pc, ps);
    loss_kernel<<<BATCH, 256, 0, stream>>>(pc, ps, f_true, sampling_f, f_range,
                                           (float*)d_out);
}

// Round 3
// 76.881 us; speedup vs baseline: 1.5971x; 1.0046x over previous
//
#include <hip/hip_runtime.h>

#define BATCH 64
#define NSAMP 1500
#define NFREQ 1251
#define NSEG  5
#define SEGLEN 300          // NSEG*SEGLEN == NSAMP, SEGLEN % 4 == 0
#define FBLK  256           // freqs per block in kernel 1
#define FCHUNKS 5           // ceil(NFREQ/FBLK) = 5 (5*256=1280 >= 1251)

// ---------------------------------------------------------------------------
// Kernel 1: Goertzel partial sums over time segments.
// Thread = (b, f); block z = segment (300 samples).
//   s_k = x_k + 2cos(w) s_{k-1} - s_{k-2}
//   C_loc = cos((M-1)w) s1 - cos(Mw) s2 ;  S_loc = sin((M-1)w) s1 - sin(Mw) s2
// rotated by segment-start phase n0*w. Trig in REVOLUTIONS (v_sin/v_cos).
// Thread (0,0,0)/tid0 also zeroes d_out so kernel 2 can atomicAdd into it
// without a separate memset dispatch (stream-ordered across dispatches).
// ---------------------------------------------------------------------------
__global__ __launch_bounds__(256) void goertzel_kernel(
    const float* __restrict__ x,          // [B,N]
    const float* __restrict__ fs,         // [B]
    const float* __restrict__ sampling_f, // [1]
    const float* __restrict__ f_range,    // f_min first
    float2* __restrict__ pcs,             // [B,NSEG,NFREQ] partial (C,S)
    float* __restrict__ out)              // [1] zeroed here
{
    __shared__ float4 xs4[SEGLEN / 4];    // 300 floats = 75 float4
    const int b   = blockIdx.x;
    const int seg = blockIdx.z;
    const int tid = threadIdx.x;
    const int n0  = seg * SEGLEN;

    if (b == 0 && seg == 0 && blockIdx.y == 0 && tid == 0) out[0] = 0.0f;

    const float4* xg = reinterpret_cast<const float4*>(x + b * NSAMP + n0);
    for (int i = tid; i < SEGLEN / 4; i += FBLK) xs4[i] = xg[i];
    __syncthreads();

    const int fidx = blockIdx.y * FBLK + tid;
    if (fidx >= NFREQ) return;

    // numpy arange fill semantics
    const float f_min = f_range[0];
    const float step  = sampling_f[0];
    const float delta = (f_min + step) - f_min;
    const float fv    = f_min + (float)fidx * delta;

    const float rho = fv / fs[b];                 // revolutions per sample
    float rf = rho - floorf(rho);
    const float coef = 2.0f * __builtin_amdgcn_cosf(rf);

    float s1 = 0.0f, s2 = 0.0f;
#pragma unroll 5
    for (int k = 0; k < SEGLEN / 4; ++k) {
        float4 v = xs4[k];
        float t;
        t = fmaf(coef, s1, v.x - s2); s2 = s1; s1 = t;
        t = fmaf(coef, s1, v.y - s2); s2 = s1; s1 = t;
        t = fmaf(coef, s1, v.z - s2); s2 = s1; s1 = t;
        t = fmaf(coef, s1, v.w - s2); s2 = s1; s1 = t;
    }

    float aM  = (float)SEGLEN * rho;        aM  -= floorf(aM);
    float aM1 = (float)(SEGLEN - 1) * rho;  aM1 -= floorf(aM1);
    float a0  = (float)n0 * rho;            a0  -= floorf(a0);
    const float cM  = __builtin_amdgcn_cosf(aM);
    const float sM  = __builtin_amdgcn_sinf(aM);
    const float cM1 = __builtin_amdgcn_cosf(aM1);
    const float sM1 = __builtin_amdgcn_sinf(aM1);
    const float c0  = __builtin_amdgcn_cosf(a0);
    const float s0  = __builtin_amdgcn_sinf(a0);

    const float Cl = cM1 * s1 - cM * s2;
    const float Sl = sM1 * s1 - sM * s2;
    const float C  = c0 * Cl - s0 * Sl;
    const float S  = s0 * Cl + c0 * Sl;

    pcs[(b * NSEG + seg) * NFREQ + fidx] = make_float2(C, S);
}

// ---------------------------------------------------------------------------
// Kernel 2: assemble psd, per-sample softmax-log-gather, fused mean via
// atomicAdd into d_out (zeroed by kernel 1).
// ---------------------------------------------------------------------------
__global__ __launch_bounds__(256) void loss_kernel(
    const float2* __restrict__ pcs,       // [B,NSEG,NFREQ]
    const float* __restrict__ f_true,     // [B]
    const float* __restrict__ sampling_f,
    const float* __restrict__ f_range,
    float* __restrict__ out)              // [1]
{
    const int b   = blockIdx.x;
    const int tid = threadIdx.x;

    __shared__ float psd_s[NFREQ];
    __shared__ float smax[256];
    __shared__ float ssum[256];
    __shared__ float sdist[256];
    __shared__ int   sidx[256];

    const float f_min = f_range[0];
    const float step  = sampling_f[0];
    const float delta = (f_min + step) - f_min;
    const float ft    = f_true[b];

    float vmax  = -INFINITY;
    float bestd = INFINITY;
    int   besti = NFREQ;
    for (int i = tid; i < NFREQ; i += 256) {
        float c = 0.0f, s = 0.0f;
#pragma unroll
        for (int g = 0; g < NSEG; ++g) {
            float2 v = pcs[(b * NSEG + g) * NFREQ + i];
            c += v.x; s += v.y;
        }
        float v = fmaf(c, c, s * s);
        psd_s[i] = v;
        vmax = fmaxf(vmax, v);
        float fv = f_min + (float)i * delta;
        float d  = fabsf(fv - ft);
        if (d < bestd) { bestd = d; besti = i; }   // per-thread first min
    }
    smax[tid] = vmax; sdist[tid] = bestd; sidx[tid] = besti;
    __syncthreads();
    for (int s = 128; s > 0; s >>= 1) {
        if (tid < s) {
            smax[tid] = fmaxf(smax[tid], smax[tid + s]);
            float d2 = sdist[tid + s]; int i2 = sidx[tid + s];
            if (d2 < sdist[tid] || (d2 == sdist[tid] && i2 < sidx[tid])) {
                sdist[tid] = d2; sidx[tid] = i2;   // np.argmin: first occurrence
            }
        }
        __syncthreads();
    }
    const float gmax = smax[0];
    const int   idx  = sidx[0];

    float se = 0.0f;
    for (int i = tid; i < NFREQ; i += 256) se += __expf(psd_s[i] - gmax);
    ssum[tid] = se;
    __syncthreads();
    for (int s = 128; s > 0; s >>= 1) {
        if (tid < s) ssum[tid] += ssum[tid + s];
        __syncthreads();
    }

    if (tid == 0) {
        float sm = __expf(psd_s[idx] - gmax) / ssum[0];
        float per = -logf(sm + 1e-8f);
        atomicAdd(out, per * (1.0f / (float)BATCH));
    }
}

extern "C" void kernel_launch(void* const* d_in, const int* in_sizes, int n_in,
                              void* d_out, int out_size, void* d_ws, size_t ws_size,
                              hipStream_t stream) {
    const float* x          = (const float*)d_in[0];
    const float* f_true     = (const float*)d_in[1];
    const float* fs         = (const float*)d_in[2];
    // d_in[3] = deltas (unused)
    const float* sampling_f = (const float*)d_in[4];
    const float* f_range    = (const float*)d_in[5];

    float2* pcs = (float2*)d_ws;   // [B*NSEG*NFREQ] float2 = 3.2 MB

    dim3 g1(BATCH, FCHUNKS, NSEG); // 64 x 5 x 5 = 1600 blocks x 4 waves
    goertzel_kernel<<<g1, FBLK, 0, stream>>>(x, fs, sampling_f, f_range, pcs,
                                             (float*)d_out);
    loss_kernel<<<BATCH, 256, 0, stream>>>(pcs, f_true, sampling_f, f_range,
                                           (float*)d_out);
}